// Round 1
// baseline (18.289 us; speedup 1.0000x reference)
//
#include <hip/hip_runtime.h>

// Problem constants (match reference)
#define BATCH      16
#define SEQ_N      1024
#define EMBED_DIM  256
#define NTILE      32            // n-values per block
#define LDS_STRIDE 260           // 256 + 4 pad: transpose read is 4-way conflict max

// out[b][d][n] = embedding[seq[b][n]][d]
// One block: (b, n-tile of 32). Load 32 gathered rows coalesced into LDS,
// store transposed as 128B-aligned float4 chunks along n.
__global__ __launch_bounds__(256) void
embed_gather_transpose(const int* __restrict__ seq,
                       const float* __restrict__ emb,
                       float* __restrict__ out) {
    __shared__ float lds[NTILE * LDS_STRIDE];
    __shared__ int   rows[NTILE];

    const int b  = blockIdx.x >> 5;          // /32 tiles per batch
    const int n0 = (blockIdx.x & 31) << 5;   // *NTILE

    if (threadIdx.x < NTILE)
        rows[threadIdx.x] = seq[b * SEQ_N + n0 + threadIdx.x];
    __syncthreads();

    // ---- load phase: 32 rows x 64 float4 = 2048 float4, 8 per thread ----
    // lanes sweep float4-columns within a row -> fully coalesced 1KB/wave reads
#pragma unroll
    for (int i = 0; i < 8; ++i) {
        const int flat = i * 256 + threadIdx.x;  // 0..2047
        const int nn   = flat >> 6;              // row in tile (64 float4/row)
        const int c4   = flat & 63;              // float4 column
        const float4 v =
            reinterpret_cast<const float4*>(emb + (size_t)rows[nn] * EMBED_DIM)[c4];
        float* dst = &lds[nn * LDS_STRIDE + c4 * 4];
        dst[0] = v.x; dst[1] = v.y; dst[2] = v.z; dst[3] = v.w;
    }
    __syncthreads();

    // ---- store phase: 256 d x 8 float4 (32 n) = 2048 float4, 8 per thread ----
    // 8 consecutive lanes emit one contiguous 128B chunk per d; chunks are
    // 128B-aligned (n0 multiple of 32).
    float* outb = out + ((size_t)b * EMBED_DIM) * SEQ_N + n0;
#pragma unroll
    for (int i = 0; i < 8; ++i) {
        const int flat = i * 256 + threadIdx.x;  // 0..2047
        const int d    = flat >> 3;
        const int q    = flat & 7;               // float4 index within 32-n chunk
        const int nn   = q << 2;
        float4 v;
        v.x = lds[(nn + 0) * LDS_STRIDE + d];
        v.y = lds[(nn + 1) * LDS_STRIDE + d];
        v.z = lds[(nn + 2) * LDS_STRIDE + d];
        v.w = lds[(nn + 3) * LDS_STRIDE + d];
        reinterpret_cast<float4*>(outb + (size_t)d * SEQ_N)[q] = v;
    }
}

extern "C" void kernel_launch(void* const* d_in, const int* in_sizes, int n_in,
                              void* d_out, int out_size, void* d_ws, size_t ws_size,
                              hipStream_t stream) {
    const int*   seq = (const int*)d_in[0];
    const float* emb = (const float*)d_in[1];
    float*       out = (float*)d_out;

    const int grid = BATCH * (SEQ_N / NTILE);  // 16 * 32 = 512 blocks
    embed_gather_transpose<<<grid, 256, 0, stream>>>(seq, emb, out);
}

// Round 2
// 11.606 us; speedup vs baseline: 1.5759x; 1.5759x over previous
//
#include <hip/hip_runtime.h>

// Problem constants (match reference)
#define BATCH      16
#define SEQ_N      1024
#define EMBED_DIM  256
#define NTILE      16            // n-values per block
#define LDS_STRIDE 260           // 256 + 4 pad: transpose read is 2-way (free) at NTILE=16

// out[b][d][n] = embedding[seq[b][n]][d]
// One block: (b, n-tile of 16). 1024 blocks -> 4 blocks/CU, 16 waves/CU.
__global__ __launch_bounds__(256) void
embed_gather_transpose(const int* __restrict__ seq,
                       const float* __restrict__ emb,
                       float* __restrict__ out) {
    __shared__ float lds[NTILE * LDS_STRIDE];   // 16.6 KB

    const int b  = blockIdx.x >> 6;          // 64 tiles per batch
    const int n0 = (blockIdx.x & 63) << 4;   // *NTILE
    const int* seqb = seq + b * SEQ_N + n0;

    // ---- load phase: 16 rows x 64 float4 = 1024 float4, 4 per thread ----
    // lanes sweep float4-columns within a row -> fully coalesced 1KB/wave reads
#pragma unroll
    for (int i = 0; i < 4; ++i) {
        const int flat = i * 256 + threadIdx.x;  // 0..1023
        const int nn   = flat >> 6;              // row in tile (64 float4/row)
        const int c4   = flat & 63;              // float4 column
        const int row  = seqb[nn];               // 64B line, L1-cached broadcast
        const float4 v =
            reinterpret_cast<const float4*>(emb + (size_t)row * EMBED_DIM)[c4];
        float* dst = &lds[nn * LDS_STRIDE + c4 * 4];
        dst[0] = v.x; dst[1] = v.y; dst[2] = v.z; dst[3] = v.w;
    }
    __syncthreads();

    // ---- store phase: 256 d x 4 float4 (16 n) = 1024 float4, 4 per thread ----
    // 4 consecutive lanes emit one contiguous 64B chunk per d; 64B-aligned.
    float* outb = out + ((size_t)b * EMBED_DIM) * SEQ_N + n0;
#pragma unroll
    for (int i = 0; i < 4; ++i) {
        const int flat = i * 256 + threadIdx.x;  // 0..1023
        const int d    = flat >> 2;
        const int q    = flat & 3;               // float4 index within 16-n chunk
        const int nn   = q << 2;
        float4 v;
        v.x = lds[(nn + 0) * LDS_STRIDE + d];
        v.y = lds[(nn + 1) * LDS_STRIDE + d];
        v.z = lds[(nn + 2) * LDS_STRIDE + d];
        v.w = lds[(nn + 3) * LDS_STRIDE + d];
        reinterpret_cast<float4*>(outb + (size_t)d * SEQ_N)[q] = v;
    }
}

extern "C" void kernel_launch(void* const* d_in, const int* in_sizes, int n_in,
                              void* d_out, int out_size, void* d_ws, size_t ws_size,
                              hipStream_t stream) {
    const int*   seq = (const int*)d_in[0];
    const float* emb = (const float*)d_in[1];
    float*       out = (float*)d_out;

    const int grid = BATCH * (SEQ_N / NTILE);  // 16 * 64 = 1024 blocks
    embed_gather_transpose<<<grid, 256, 0, stream>>>(seq, emb, out);
}

// Round 4
// 10.122 us; speedup vs baseline: 1.8068x; 1.1466x over previous
//
#include <hip/hip_runtime.h>

// Problem constants (match reference)
#define BATCH       16
#define SEQ_N       1024
#define EMBED_DIM   256
#define NTILE       16     // n-values per block
#define LDS_STRIDE4 65     // float4 stride -> 260-float element stride (2-way read, free)

// native vector type: __builtin_nontemporal_store requires scalar/native-vector
typedef float f32x4 __attribute__((ext_vector_type(4)));

// out[b][d][n] = embedding[seq[b][n]][d]
// One block: (b, n-tile of 16). 1024 blocks x 512 threads -> 4 blocks/CU,
// 32 waves/CU (occupancy max).
__global__ __launch_bounds__(512) void
embed_gather_transpose(const int* __restrict__ seq,
                       const float* __restrict__ emb,
                       float* __restrict__ out) {
    __shared__ f32x4 lds4[NTILE * LDS_STRIDE4];   // 16.6 KB
    const float* lds = reinterpret_cast<const float*>(lds4);

    const int b  = blockIdx.x >> 6;          // 64 tiles per batch
    const int n0 = (blockIdx.x & 63) << 4;   // *NTILE
    const int* seqb = seq + b * SEQ_N + n0;

    // ---- load phase: 16 rows x 64 float4 = 1024 float4, 2 per thread ----
    // f32x4 LDS writes -> ds_write_b128, conflict-free; global reads fully
    // coalesced (1KB per wave per row).
#pragma unroll
    for (int i = 0; i < 2; ++i) {
        const int flat = i * 512 + threadIdx.x;  // 0..1023
        const int nn   = flat >> 6;              // row in tile (64 float4/row)
        const int c4   = flat & 63;              // float4 column
        const int row  = seqb[nn];               // 64B line, L1 broadcast
        lds4[nn * LDS_STRIDE4 + c4] =
            reinterpret_cast<const f32x4*>(emb + (size_t)row * EMBED_DIM)[c4];
    }
    __syncthreads();

    // ---- store phase: 256 d x 4 float4 (16 n) = 1024 float4, 2 per thread ----
    // 4 consecutive lanes emit one contiguous 64B chunk per d; 64B-aligned.
    // Transpose read: bank = (4*nn + d) mod 32 -> 2 lanes/bank = free.
    // Non-temporal: output is write-once, keep L2 for embedding re-reads.
    float* outb = out + ((size_t)b * EMBED_DIM) * SEQ_N + n0;
#pragma unroll
    for (int i = 0; i < 2; ++i) {
        const int flat = i * 512 + threadIdx.x;  // 0..1023
        const int d    = flat >> 2;
        const int q    = flat & 3;               // float4 index within 16-n chunk
        const int nn   = q << 2;
        f32x4 v;
        v.x = lds[(nn + 0) * (LDS_STRIDE4 * 4) + d];
        v.y = lds[(nn + 1) * (LDS_STRIDE4 * 4) + d];
        v.z = lds[(nn + 2) * (LDS_STRIDE4 * 4) + d];
        v.w = lds[(nn + 3) * (LDS_STRIDE4 * 4) + d];
        __builtin_nontemporal_store(
            v, reinterpret_cast<f32x4*>(outb + (size_t)d * SEQ_N) + q);
    }
}

extern "C" void kernel_launch(void* const* d_in, const int* in_sizes, int n_in,
                              void* d_out, int out_size, void* d_ws, size_t ws_size,
                              hipStream_t stream) {
    const int*   seq = (const int*)d_in[0];
    const float* emb = (const float*)d_in[1];
    float*       out = (float*)d_out;

    const int grid = BATCH * (SEQ_N / NTILE);  // 16 * 64 = 1024 blocks
    embed_gather_transpose<<<grid, 512, 0, stream>>>(seq, emb, out);
}